// Round 1
// baseline (542.121 us; speedup 1.0000x reference)
//
#include <hip/hip_runtime.h>

// Problem constants (fixed by the reference)
#define B_   8
#define N_   4096
#define D_   1024
#define HID  128
#define QKVW 384
#define M_   (B_*N_)   // 32768 rows
#define NCH  32        // 128-row chunks per batch for softmax/context partials

typedef unsigned short u16;
typedef unsigned int   u32;
typedef __attribute__((ext_vector_type(8))) short bf16x8;  // 8 bf16 = 4 VGPRs
typedef __attribute__((ext_vector_type(4))) float f32x4;

__device__ __forceinline__ u16 f2bf(float f){
  u32 u = __float_as_uint(f);
  u32 r = (u + 0x7fffu + ((u >> 16) & 1u)) >> 16;   // RNE
  return (u16)r;
}

// ---------------------------------------------------------------------------
// 0. Transpose weights to bf16, k-contiguous (for contiguous B fragments)
//    wqT[n][k] = w_qkv[k][n]   (384 x 1024)
//    woT[n][k] = w_out[k][n]   (1024 x 128)
// ---------------------------------------------------------------------------
__global__ void convw_kernel(const float* __restrict__ wqkv, const float* __restrict__ wout,
                             u16* __restrict__ wqT, u16* __restrict__ woT){
  int idx = blockIdx.x * 256 + threadIdx.x;
  if (idx < QKVW * D_){
    int n = idx >> 10, k = idx & 1023;
    wqT[idx] = f2bf(wqkv[(size_t)k * QKVW + n]);
  }
  if (idx < D_ * HID){
    int n = idx >> 7, k = idx & 127;
    woT[idx] = f2bf(wout[(size_t)k * D_ + n]);
  }
}

// ---------------------------------------------------------------------------
// 1. LayerNorm over dim=1024, one block per row, output bf16
// ---------------------------------------------------------------------------
__global__ __launch_bounds__(256)
void ln_kernel(const float* __restrict__ x, const float* __restrict__ gamma,
               const float* __restrict__ beta, u16* __restrict__ xn){
  int row = blockIdx.x, t = threadIdx.x;
  const float4 v = ((const float4*)(x + (size_t)row * D_))[t];
  float s = v.x + v.y + v.z + v.w;
  float q = v.x*v.x + v.y*v.y + v.z*v.z + v.w*v.w;
  #pragma unroll
  for (int off = 32; off > 0; off >>= 1){
    s += __shfl_down(s, off, 64);
    q += __shfl_down(q, off, 64);
  }
  __shared__ float ss[4], qq[4];
  int wid = t >> 6, lane = t & 63;
  if (lane == 0){ ss[wid] = s; qq[wid] = q; }
  __syncthreads();
  if (t == 0){
    float S = ss[0] + ss[1] + ss[2] + ss[3];
    float Q = qq[0] + qq[1] + qq[2] + qq[3];
    float mean = S * (1.f / D_);
    float var  = Q * (1.f / D_) - mean * mean;
    ss[0] = mean;
    qq[0] = rsqrtf(var + 1e-5f);
  }
  __syncthreads();
  float mean = ss[0], rstd = qq[0];
  const float4 g  = ((const float4*)gamma)[t];
  const float4 be = ((const float4*)beta)[t];
  float y0 = (v.x - mean) * rstd * g.x + be.x;
  float y1 = (v.y - mean) * rstd * g.y + be.y;
  float y2 = (v.z - mean) * rstd * g.z + be.z;
  float y3 = (v.w - mean) * rstd * g.w + be.w;
  uint2 o;
  o.x = (u32)f2bf(y0) | ((u32)f2bf(y1) << 16);
  o.y = (u32)f2bf(y2) | ((u32)f2bf(y3) << 16);
  ((uint2*)(xn + (size_t)row * D_))[t] = o;
}

// ---------------------------------------------------------------------------
// 2. bf16 MFMA GEMM: C[M x N] = A[M x K] * Bt[N x K]^T  (+ bias + resid if EPI)
//    BM=BN=128, BK=32, 256 threads = 4 waves in 2x2, each wave 64x64 (4x4 MFMA)
//    Verified gfx950 16x16x32 layouts:
//      A frag: lane holds A[m=lane&15][k=(lane>>4)*8 + j]
//      B frag: lane holds B[k=(lane>>4)*8 + j][n=lane&15]
//      D:      lane reg r -> D[m=(lane>>4)*4 + r][n=lane&15]
// ---------------------------------------------------------------------------
template<int K, bool EPI>
__global__ __launch_bounds__(256)
void gemm_bf16_kernel(const u16* __restrict__ A, const u16* __restrict__ Bt,
                      float* __restrict__ C, int ldc,
                      const float* __restrict__ bias, const float* __restrict__ resid){
  __shared__ __align__(16) u16 As[128][32];
  __shared__ __align__(16) u16 Bs[128][32];
  int t = threadIdx.x;
  int lane = t & 63, wid = t >> 6;
  int rowTile = blockIdx.y * 128, colTile = blockIdx.x * 128;
  int wr = (wid >> 1) * 64, wc = (wid & 1) * 64;
  int fr = lane & 15, kq = (lane >> 4) * 8;
  f32x4 acc[4][4];
  #pragma unroll
  for (int i = 0; i < 4; i++)
    #pragma unroll
    for (int j = 0; j < 4; j++)
      #pragma unroll
      for (int r = 0; r < 4; r++) acc[i][j][r] = 0.f;

  for (int k0 = 0; k0 < K; k0 += 32){
    uint4 av[2], bv[2];
    #pragma unroll
    for (int c = 0; c < 2; c++){
      int l = c * 256 + t;
      int r = l >> 2, s = (l & 3) * 8;
      av[c] = *(const uint4*)(A  + (size_t)(rowTile + r) * K + k0 + s);
      bv[c] = *(const uint4*)(Bt + (size_t)(colTile + r) * K + k0 + s);
    }
    __syncthreads();
    #pragma unroll
    for (int c = 0; c < 2; c++){
      int l = c * 256 + t;
      int r = l >> 2, s = (l & 3) * 8;
      *(uint4*)&As[r][s] = av[c];
      *(uint4*)&Bs[r][s] = bv[c];
    }
    __syncthreads();
    bf16x8 af[4], bf[4];
    #pragma unroll
    for (int mi = 0; mi < 4; mi++) af[mi] = *(const bf16x8*)&As[wr + mi*16 + fr][kq];
    #pragma unroll
    for (int ni = 0; ni < 4; ni++) bf[ni] = *(const bf16x8*)&Bs[wc + ni*16 + fr][kq];
    #pragma unroll
    for (int mi = 0; mi < 4; mi++)
      #pragma unroll
      for (int ni = 0; ni < 4; ni++)
        acc[mi][ni] = __builtin_amdgcn_mfma_f32_16x16x32_bf16(af[mi], bf[ni], acc[mi][ni], 0, 0, 0);
  }

  #pragma unroll
  for (int mi = 0; mi < 4; mi++){
    #pragma unroll
    for (int ni = 0; ni < 4; ni++){
      #pragma unroll
      for (int r = 0; r < 4; r++){
        int row = rowTile + wr + mi*16 + (lane >> 4) * 4 + r;
        int col = colTile + wc + ni*16 + (lane & 15);
        float v = acc[mi][ni][r];
        if (EPI) v += bias[col] + resid[(size_t)row * ldc + col];
        C[(size_t)row * ldc + col] = v;
      }
    }
  }
}

// ---------------------------------------------------------------------------
// 3. Softmax-over-n partials + context partials per (batch, 128-row chunk).
//    No max-subtraction: |k| <= ||xn||*||w_col|| ~ 38 << 88, exp is fp32-safe.
//    pctx[b][c][h][d][e] = sum_n exp(k[n,h,d]) * v[n,h,e]  (chunk partial)
//    psum[b][c][col]     = sum_n exp(k[n,col])
// ---------------------------------------------------------------------------
__global__ __launch_bounds__(256)
void ctx_partial_kernel(const float* __restrict__ qkv, float* __restrict__ pctx,
                        float* __restrict__ psum){
  int c = blockIdx.x;   // chunk
  int b = blockIdx.y;   // batch
  int t = threadIdx.x;
  __shared__ float pk[8][128], pv[8][128];
  int h  = t >> 6;
  int idx = t & 63;
  int d0 = (idx >> 3) * 4;
  int e0 = (idx & 7) * 4;
  float acc[4][4];
  #pragma unroll
  for (int i = 0; i < 4; i++)
    #pragma unroll
    for (int j = 0; j < 4; j++) acc[i][j] = 0.f;
  float ssum = 0.f;
  int base_row = b * N_ + c * 128;
  for (int rr = 0; rr < 16; ++rr){
    int rb = base_row + rr * 8;
    __syncthreads();
    #pragma unroll
    for (int i = 0; i < 4; i++){
      int l = i * 256 + t;
      int r = l >> 7, col = l & 127;
      pk[r][col] = __expf(qkv[(size_t)(rb + r) * QKVW + HID   + col]);
      pv[r][col] =        qkv[(size_t)(rb + r) * QKVW + 2*HID + col];
    }
    __syncthreads();
    #pragma unroll
    for (int r = 0; r < 8; r++){
      float kd[4], ve[4];
      #pragma unroll
      for (int i = 0; i < 4; i++){ kd[i] = pk[r][h*32 + d0 + i]; ve[i] = pv[r][h*32 + e0 + i]; }
      #pragma unroll
      for (int i = 0; i < 4; i++)
        #pragma unroll
        for (int j = 0; j < 4; j++)
          acc[i][j] += kd[i] * ve[j];
    }
    if (t < 128){
      #pragma unroll
      for (int r = 0; r < 8; r++) ssum += pk[r][t];
    }
  }
  float* outp = pctx + ((size_t)(b * NCH + c) * 4 + h) * 1024;
  #pragma unroll
  for (int i = 0; i < 4; i++)
    #pragma unroll
    for (int j = 0; j < 4; j++)
      outp[(d0 + i) * 32 + (e0 + j)] = acc[i][j];
  if (t < 128) psum[(size_t)(b * NCH + c) * 128 + t] = ssum;
}

// ---------------------------------------------------------------------------
// 4. Reduce chunk partials -> normalized context, transposed + q-scale folded:
//    ctxT[b][h][e][d] = (sum_c pctx) / (sum_c psum[h*32+d]) * DIM_HEAD^-0.5
// ---------------------------------------------------------------------------
__global__ void ctx_reduce_kernel(const float* __restrict__ pctx, const float* __restrict__ psum,
                                  float* __restrict__ ctxT){
  int bh = blockIdx.x;           // b*4 + h
  int b = bh >> 2, h = bh & 3;
  int t = threadIdx.x;           // 0..1023
  int d = t >> 5, e = t & 31;
  float s = 0.f, S = 0.f;
  for (int c = 0; c < NCH; c++){
    s += pctx[((size_t)(b * NCH + c) * 4 + h) * 1024 + t];
    S += psum[(size_t)(b * NCH + c) * 128 + h * 32 + d];
  }
  ctxT[((size_t)bh * 32 + e) * 32 + d] = s / S * 0.17677669529663689f; // * 32^-0.5
}

// ---------------------------------------------------------------------------
// 5. attn[n][h*32+e] = sum_d ctxT[b][h][e][d] * q[n][h*32+d], output bf16.
//    ctx staged in LDS with +1 pad; d-index rotated by 8*h to avoid 4-way
//    bank conflicts across heads.
// ---------------------------------------------------------------------------
__global__ __launch_bounds__(256)
void attn_q_kernel(const float* __restrict__ qkv, const float* __restrict__ ctxT,
                   u16* __restrict__ attn){
  int blk = blockIdx.x, t = threadIdx.x;
  int row0 = blk * 32;
  int b = row0 >> 12;
  __shared__ float ctx_l[4][32][33];
  __shared__ float ql[2][128];
  #pragma unroll
  for (int i = 0; i < 16; i++){
    int l = i * 256 + t;
    int hh = l >> 10, rem = l & 1023;
    ctx_l[hh][rem >> 5][rem & 31] = ctxT[(size_t)(b * 4 + hh) * 1024 + rem];
  }
  int col = t & 127, rl = t >> 7;
  int h = col >> 5, e = col & 31;
  for (int it = 0; it < 16; ++it){
    int r = row0 + it * 2 + rl;
    __syncthreads();   // also covers the ctx_l preload on it==0
    ql[rl][col] = qkv[(size_t)r * QKVW + col];   // q = cols 0..127
    __syncthreads();
    float acc = 0.f;
    #pragma unroll
    for (int dd = 0; dd < 32; ++dd){
      int d = (dd + h * 8) & 31;
      acc += ctx_l[h][e][d] * ql[rl][h * 32 + d];
    }
    attn[(size_t)r * HID + col] = f2bf(acc);
  }
}

// ---------------------------------------------------------------------------
// Launch. Scratch plan:
//   d_out[0 .. 64MB)    : xn bf16   (dead after qkv GEMM)
//   d_out[64 .. 112MB)  : qkv fp32  (dead after attn_q) — final GEMM then
//                         overwrites all of d_out with the real output.
//   d_ws: wqT(768K) | woT(256K) | pctx(4M) | psum(128K) | ctxT(128K) | attn(8M)
// ---------------------------------------------------------------------------
extern "C" void kernel_launch(void* const* d_in, const int* in_sizes, int n_in,
                              void* d_out, int out_size, void* d_ws, size_t ws_size,
                              hipStream_t stream){
  const float* x     = (const float*)d_in[0];
  const float* gamma = (const float*)d_in[1];
  const float* beta  = (const float*)d_in[2];
  const float* wqkv  = (const float*)d_in[3];
  const float* wout  = (const float*)d_in[4];
  const float* bout  = (const float*)d_in[5];
  float* out = (float*)d_out;

  char* ob  = (char*)d_out;
  u16*   xn  = (u16*)ob;                               // 67,108,864 B
  float* qkv = (float*)(ob + (size_t)M_ * D_ * 2);     // 50,331,648 B (fits: 117.4MB <= 134.2MB)

  char* wsb = (char*)d_ws;
  u16*   wqT  = (u16*)  (wsb);                 // 786,432 B
  u16*   woT  = (u16*)  (wsb + 0x000C0000);    // 262,144 B
  float* pctx = (float*)(wsb + 0x00100000);    // 4,194,304 B
  float* psum = (float*)(wsb + 0x00500000);    // 131,072 B
  float* ctxT = (float*)(wsb + 0x00540000);    // 131,072 B
  u16*   attn = (u16*)  (wsb + 0x00600000);    // 8,388,608 B   (total ~14.7 MB)

  convw_kernel<<<1536, 256, 0, stream>>>(wqkv, wout, wqT, woT);
  ln_kernel<<<M_, 256, 0, stream>>>(x, gamma, beta, xn);
  gemm_bf16_kernel<1024, false><<<dim3(QKVW/128, M_/128), 256, 0, stream>>>(
      xn, wqT, qkv, QKVW, nullptr, nullptr);
  ctx_partial_kernel<<<dim3(NCH, B_), 256, 0, stream>>>(qkv, pctx, psum);
  ctx_reduce_kernel<<<32, 1024, 0, stream>>>(pctx, psum, ctxT);
  attn_q_kernel<<<M_/32, 256, 0, stream>>>(qkv, ctxT, attn);
  gemm_bf16_kernel<128, true><<<dim3(D_/128, M_/128), 256, 0, stream>>>(
      attn, woT, out, D_, bout, x);
}

// Round 2
// 346.116 us; speedup vs baseline: 1.5663x; 1.5663x over previous
//
#include <hip/hip_runtime.h>

#define B_   8
#define N_   4096
#define D_   1024
#define HID  128
#define QKVW 384
#define M_   (B_*N_)   // 32768 rows

typedef unsigned short u16;
typedef unsigned int   u32;
typedef __attribute__((ext_vector_type(8))) short bf16x8;
typedef __attribute__((ext_vector_type(4))) float f32x4;

__device__ __forceinline__ u16 f2bf(float f){
  u32 u = __float_as_uint(f);
  u32 r = (u + 0x7fffu + ((u >> 16) & 1u)) >> 16;   // RNE
  return (u16)r;
}

// async global->LDS, 16B per lane; LDS dst = wave-uniform base + lane*16
#define GLOAD_LDS16(g, l) __builtin_amdgcn_global_load_lds( \
    (const __attribute__((address_space(1))) unsigned int*)(g), \
    (__attribute__((address_space(3))) unsigned int*)(l), 16, 0, 0)

// ---------------------------------------------------------------------------
// 0. Weights -> bf16, k-contiguous transposed
// ---------------------------------------------------------------------------
__global__ void convw_kernel(const float* __restrict__ wqkv, const float* __restrict__ wout,
                             u16* __restrict__ wqT, u16* __restrict__ woT){
  int idx = blockIdx.x * 256 + threadIdx.x;
  if (idx < QKVW * D_){
    int n = idx >> 10, k = idx & 1023;
    wqT[idx] = f2bf(wqkv[(size_t)k * QKVW + n]);
  }
  if (idx < D_ * HID){
    int n = idx >> 7, k = idx & 127;
    woT[idx] = f2bf(wout[(size_t)k * D_ + n]);
  }
}

// ---------------------------------------------------------------------------
// 1. LayerNorm over dim=1024, one block per row, bf16 out
// ---------------------------------------------------------------------------
__global__ __launch_bounds__(256)
void ln_kernel(const float* __restrict__ x, const float* __restrict__ gamma,
               const float* __restrict__ beta, u16* __restrict__ xn){
  int row = blockIdx.x, t = threadIdx.x;
  const float4 v = ((const float4*)(x + (size_t)row * D_))[t];
  float s = v.x + v.y + v.z + v.w;
  float q = v.x*v.x + v.y*v.y + v.z*v.z + v.w*v.w;
  #pragma unroll
  for (int off = 32; off > 0; off >>= 1){
    s += __shfl_down(s, off, 64);
    q += __shfl_down(q, off, 64);
  }
  __shared__ float ss[4], qq[4];
  int wid = t >> 6, lane = t & 63;
  if (lane == 0){ ss[wid] = s; qq[wid] = q; }
  __syncthreads();
  if (t == 0){
    float S = ss[0] + ss[1] + ss[2] + ss[3];
    float Q = qq[0] + qq[1] + qq[2] + qq[3];
    float mean = S * (1.f / D_);
    float var  = Q * (1.f / D_) - mean * mean;
    ss[0] = mean;
    qq[0] = rsqrtf(var + 1e-5f);
  }
  __syncthreads();
  float mean = ss[0], rstd = qq[0];
  const float4 g  = ((const float4*)gamma)[t];
  const float4 be = ((const float4*)beta)[t];
  float y0 = (v.x - mean) * rstd * g.x + be.x;
  float y1 = (v.y - mean) * rstd * g.y + be.y;
  float y2 = (v.z - mean) * rstd * g.z + be.z;
  float y3 = (v.w - mean) * rstd * g.w + be.w;
  uint2 o;
  o.x = (u32)f2bf(y0) | ((u32)f2bf(y1) << 16);
  o.y = (u32)f2bf(y2) | ((u32)f2bf(y3) << 16);
  ((uint2*)(xn + (size_t)row * D_))[t] = o;
}

// ---------------------------------------------------------------------------
// 2. QKV GEMM: qkv[M x 384] = xn[M x 1024] * wqT[384 x 1024]^T
//    BM=64, BN=384 (full width -> A fetched exactly once), BK=32.
//    4 waves; wave w covers cols [w*96, w*96+96), rows 0..63 -> 4x6 MFMA.
//    LDS packed 64B rows; 16B chunks XOR-swizzled by ((row>>1)&3) so the
//    16-lane fragment read groups spread 2-way over banks (free).
//    Staged with global_load_lds width=16 (m97 pattern, 2 barriers/step).
// ---------------------------------------------------------------------------
__global__ __launch_bounds__(256)
void gemm_qkv(const u16* __restrict__ A, const u16* __restrict__ Bt,
              float* __restrict__ C){
  __shared__ __align__(16) u16 As[64 * 32];    // 4 KB
  __shared__ __align__(16) u16 Bs[384 * 32];   // 24 KB
  const int t = threadIdx.x, lane = t & 63, w = t >> 6;
  const int rowTile = blockIdx.x * 64;
  // staging: lane covers row (lr) chunk (lc logical, stored at phys lane&3)
  const int lr = lane >> 2;
  const int lc = (lane & 3) ^ ((lane >> 3) & 3);
  const u16* pA = A  + (size_t)(rowTile + w*16 + lr) * 1024 + lc * 8;
  const u16* pB = Bt + (size_t)(w*96 + lr) * 1024 + lc * 8;
  u16* dA = &As[w * 16 * 32];
  u16* dB = &Bs[w * 96 * 32];
  const int fr = lane & 15, q = lane >> 4;
  const int pc = (q ^ ((fr >> 1) & 3)) * 8;    // phys chunk offset (halfwords)

  f32x4 acc[4][6];
  #pragma unroll
  for (int i = 0; i < 4; i++)
    #pragma unroll
    for (int j = 0; j < 6; j++)
      #pragma unroll
      for (int r = 0; r < 4; r++) acc[i][j][r] = 0.f;

  for (int k0 = 0; k0 < 1024; k0 += 32){
    __syncthreads();                  // previous iteration's reads done
    GLOAD_LDS16(pA, dA);
    #pragma unroll
    for (int j = 0; j < 6; j++)
      GLOAD_LDS16(pB + (size_t)j * 16 * 1024, dB + j * 16 * 32);
    pA += 32; pB += 32;
    __syncthreads();                  // vmcnt(0) drained before barrier
    bf16x8 af[4], bf[6];
    #pragma unroll
    for (int mi = 0; mi < 4; mi++) af[mi] = *(const bf16x8*)&As[(mi*16 + fr)*32 + pc];
    #pragma unroll
    for (int ni = 0; ni < 6; ni++) bf[ni] = *(const bf16x8*)&Bs[(w*96 + ni*16 + fr)*32 + pc];
    #pragma unroll
    for (int mi = 0; mi < 4; mi++)
      #pragma unroll
      for (int ni = 0; ni < 6; ni++)
        acc[mi][ni] = __builtin_amdgcn_mfma_f32_16x16x32_bf16(af[mi], bf[ni], acc[mi][ni], 0, 0, 0);
  }

  #pragma unroll
  for (int mi = 0; mi < 4; mi++){
    #pragma unroll
    for (int ni = 0; ni < 6; ni++){
      #pragma unroll
      for (int r = 0; r < 4; r++){
        int row = rowTile + mi*16 + q*4 + r;
        int col = w*96 + ni*16 + fr;
        C[(size_t)row * QKVW + col] = acc[mi][ni][r];
      }
    }
  }
}

// ---------------------------------------------------------------------------
// 3. Final GEMM: out[M x 1024] = attn[M x 128] * woT[1024 x 128]^T + bias + x
//    K=128 in one LDS shot (no K-loop, one barrier). 128x128 tile, 2x2 waves.
//    Chunk swizzle by (row&7) for conflict-free fragment reads.
// ---------------------------------------------------------------------------
__global__ __launch_bounds__(256)
void gemm_out(const u16* __restrict__ A, const u16* __restrict__ Bt,
              float* __restrict__ C, const float* __restrict__ bias,
              const float* __restrict__ resid){
  __shared__ __align__(16) u16 As[128 * 128];  // 32 KB
  __shared__ __align__(16) u16 Bs[128 * 128];  // 32 KB
  const int t = threadIdx.x, lane = t & 63, w = t >> 6;
  const int rowTile = blockIdx.y * 128, colTile = blockIdx.x * 128;
  const int r4 = lane >> 4;                       // row within 4-row group
  // DMA instr i (= w*8+j) covers rows i*4 + r4; phys chunk = lane&15
  u16* dA = &As[w * 32 * 128];
  u16* dB = &Bs[w * 32 * 128];
  #pragma unroll
  for (int j = 0; j < 8; j++){
    int i = w * 8 + j;
    int lc = (lane & 15) ^ ((4 * (i & 1)) | r4);  // logical chunk (row&7 swizzle)
    const u16* gA = A  + (size_t)(rowTile + i*4 + r4) * 128 + lc * 8;
    const u16* gB = Bt + (size_t)(colTile + i*4 + r4) * 128 + lc * 8;
    GLOAD_LDS16(gA, dA + j * 4 * 128);
    GLOAD_LDS16(gB, dB + j * 4 * 128);
  }
  const int wr = (w >> 1) * 64, wc = (w & 1) * 64;
  const int fr = lane & 15, q = lane >> 4;
  f32x4 acc[4][4];
  #pragma unroll
  for (int i = 0; i < 4; i++)
    #pragma unroll
    for (int j = 0; j < 4; j++)
      #pragma unroll
      for (int r = 0; r < 4; r++) acc[i][j][r] = 0.f;
  __syncthreads();
  #pragma unroll
  for (int kk = 0; kk < 4; kk++){
    bf16x8 af[4], bf[4];
    #pragma unroll
    for (int mi = 0; mi < 4; mi++){
      int pcc = ((kk*4 + q) ^ (fr & 7)) * 8;
      af[mi] = *(const bf16x8*)&As[(wr + mi*16 + fr) * 128 + pcc];
    }
    #pragma unroll
    for (int ni = 0; ni < 4; ni++){
      int pcc = ((kk*4 + q) ^ (fr & 7)) * 8;
      bf[ni] = *(const bf16x8*)&Bs[(wc + ni*16 + fr) * 128 + pcc];
    }
    #pragma unroll
    for (int mi = 0; mi < 4; mi++)
      #pragma unroll
      for (int ni = 0; ni < 4; ni++)
        acc[mi][ni] = __builtin_amdgcn_mfma_f32_16x16x32_bf16(af[mi], bf[ni], acc[mi][ni], 0, 0, 0);
  }
  #pragma unroll
  for (int mi = 0; mi < 4; mi++){
    #pragma unroll
    for (int ni = 0; ni < 4; ni++){
      #pragma unroll
      for (int r = 0; r < 4; r++){
        int row = rowTile + wr + mi*16 + q*4 + r;
        int col = colTile + wc + ni*16 + fr;
        C[(size_t)row * D_ + col] =
            acc[mi][ni][r] + bias[col] + resid[(size_t)row * D_ + col];
      }
    }
  }
}

// ---------------------------------------------------------------------------
// 4. Softmax/context partials per (256-row chunk, head, batch). 512 blocks.
//    pctx[bh][c][d][e] = sum_n exp(k[n,d]) * v[n,e];  psum[bh][c][d] = sum exp
// ---------------------------------------------------------------------------
__global__ __launch_bounds__(256)
void ctx_partial(const float* __restrict__ qkv, float* __restrict__ pctx,
                 float* __restrict__ psum){
  const int c = blockIdx.x, h = blockIdx.y, b = blockIdx.z;
  const int t = threadIdx.x;
  __shared__ float ek[64][32], vv[64][32];
  const int d = t >> 3, e0 = (t & 7) * 4;
  const int rl = t >> 2, cg = (t & 3) * 8;
  float a0=0.f, a1=0.f, a2=0.f, a3=0.f, ks=0.f;
  const size_t rowbase = (size_t)b * N_ + (size_t)c * 256;
  for (int s = 0; s < 4; ++s){
    __syncthreads();
    const float* src = qkv + (rowbase + s*64 + rl) * QKVW + h*32 + cg;
    float4 ka = *(const float4*)(src + 128);
    float4 kb = *(const float4*)(src + 132);
    float4 va = *(const float4*)(src + 256);
    float4 vb = *(const float4*)(src + 260);
    float4 ea = make_float4(__expf(ka.x), __expf(ka.y), __expf(ka.z), __expf(ka.w));
    float4 eb = make_float4(__expf(kb.x), __expf(kb.y), __expf(kb.z), __expf(kb.w));
    *(float4*)&ek[rl][cg]     = ea;
    *(float4*)&ek[rl][cg + 4] = eb;
    *(float4*)&vv[rl][cg]     = va;
    *(float4*)&vv[rl][cg + 4] = vb;
    __syncthreads();
    #pragma unroll 8
    for (int n = 0; n < 64; ++n){
      float kd = ek[n][d];
      float4 vn = *(const float4*)&vv[n][e0];
      a0 += kd * vn.x; a1 += kd * vn.y; a2 += kd * vn.z; a3 += kd * vn.w;
      ks += kd;
    }
  }
  float* op = pctx + (((size_t)(b*4 + h) * 16 + c) * 1024) + d*32 + e0;
  *(float4*)op = make_float4(a0, a1, a2, a3);
  if (e0 == 0) psum[((size_t)(b*4 + h) * 16 + c) * 32 + d] = ks;
}

// ---------------------------------------------------------------------------
// 5. Reduce partials -> ctxT[bh][e][d] (normalized, q-scale folded)
// ---------------------------------------------------------------------------
__global__ void ctx_reduce(const float* __restrict__ pctx, const float* __restrict__ psum,
                           float* __restrict__ ctxT){
  int bh = blockIdx.x, t = threadIdx.x;   // 1024 threads: t = d*32 + e
  int d = t >> 5, e = t & 31;
  float s = 0.f, S = 0.f;
  for (int c = 0; c < 16; ++c){
    s += pctx[((size_t)bh * 16 + c) * 1024 + t];
    S += psum[((size_t)bh * 16 + c) * 32 + d];
  }
  ctxT[(size_t)bh * 1024 + e*32 + d] = s / S * 0.17677669529663689f; // * 32^-0.5
}

// ---------------------------------------------------------------------------
// 6. attn[n][h*32+e] = sum_d ctxT[bh][e][d] * q[n][h*32+d] -> bf16.
//    64 rows per block, ctx row cached in 32 regs, single barrier.
// ---------------------------------------------------------------------------
__global__ __launch_bounds__(256)
void attn_q(const float* __restrict__ qkv, const float* __restrict__ ctxT,
            u16* __restrict__ attn){
  const int t = threadIdx.x;
  const int row0 = blockIdx.x * 64;
  const int b = row0 >> 12;
  __shared__ float ctx_l[4 * 32 * 36];   // [h*32+e][36] padded rows (16B aligned)
  __shared__ float q_l[64 * 128];
  #pragma unroll
  for (int i = 0; i < 16; ++i){
    int idx = i * 256 + t;               // 0..4095 = (h*32+e)*32 + d
    ctx_l[(idx >> 5) * 36 + (idx & 31)] = ctxT[(size_t)b * 4096 + idx];
  }
  #pragma unroll
  for (int i = 0; i < 8; ++i){
    int idx = i * 256 + t;               // 0..2047
    int row = idx >> 5, c4 = idx & 31;
    *(float4*)&q_l[row * 128 + c4 * 4] =
        *(const float4*)&qkv[(size_t)(row0 + row) * QKVW + c4 * 4];
  }
  __syncthreads();
  const int col = t & 127, h = col >> 5, e = col & 31, rh = t >> 7;
  float cr[32];
  #pragma unroll
  for (int k4 = 0; k4 < 8; ++k4){
    float4 cv = *(const float4*)&ctx_l[(h*32 + e) * 36 + k4 * 4];
    cr[k4*4+0] = cv.x; cr[k4*4+1] = cv.y; cr[k4*4+2] = cv.z; cr[k4*4+3] = cv.w;
  }
  for (int j = 0; j < 32; ++j){
    int row = rh * 32 + j;
    float a = 0.f;
    #pragma unroll
    for (int k4 = 0; k4 < 8; ++k4){
      float4 qv = *(const float4*)&q_l[row * 128 + h*32 + k4 * 4];
      a += cr[k4*4+0]*qv.x + cr[k4*4+1]*qv.y + cr[k4*4+2]*qv.z + cr[k4*4+3]*qv.w;
    }
    attn[(size_t)(row0 + row) * HID + col] = f2bf(a);
  }
}

// ---------------------------------------------------------------------------
// Launch. d_out reuse: [0,64MB)=xn bf16, [64,112MB)=qkv fp32 (both dead before
// gemm_out overwrites d_out). ws: wqT|woT|pctx|psum|ctxT|attn ~ 11.6 MB.
// ---------------------------------------------------------------------------
extern "C" void kernel_launch(void* const* d_in, const int* in_sizes, int n_in,
                              void* d_out, int out_size, void* d_ws, size_t ws_size,
                              hipStream_t stream){
  const float* x     = (const float*)d_in[0];
  const float* gamma = (const float*)d_in[1];
  const float* beta  = (const float*)d_in[2];
  const float* wqkv  = (const float*)d_in[3];
  const float* wout  = (const float*)d_in[4];
  const float* bout  = (const float*)d_in[5];
  float* out = (float*)d_out;

  char* ob  = (char*)d_out;
  u16*   xn  = (u16*)ob;                               // 64 MB
  float* qkv = (float*)(ob + (size_t)M_ * D_ * 2);     // 48 MB

  char* wsb = (char*)d_ws;
  u16*   wqT  = (u16*)  (wsb);                 // 768 KB
  u16*   woT  = (u16*)  (wsb + 0x000C0000);    // 256 KB
  float* pctx = (float*)(wsb + 0x00100000);    // 2 MB
  float* psum = (float*)(wsb + 0x00300000);    // 64 KB
  float* ctxT = (float*)(wsb + 0x00310000);    // 128 KB
  u16*   attn = (u16*)  (wsb + 0x00330000);    // 8 MB

  convw_kernel<<<1536, 256, 0, stream>>>(wqkv, wout, wqT, woT);
  ln_kernel<<<M_, 256, 0, stream>>>(x, gamma, beta, xn);
  gemm_qkv<<<M_/64, 256, 0, stream>>>(xn, wqT, qkv);
  ctx_partial<<<dim3(16, 4, 8), 256, 0, stream>>>(qkv, pctx, psum);
  ctx_reduce<<<32, 1024, 0, stream>>>(pctx, psum, ctxT);
  attn_q<<<M_/64, 256, 0, stream>>>(qkv, ctxT, attn);
  gemm_out<<<dim3(D_/128, M_/128), 256, 0, stream>>>(attn, woT, out, bout, x);
}